// Round 11
// baseline (1322.124 us; speedup 1.0000x reference)
//
#include <hip/hip_runtime.h>
#include <hip/hip_bf16.h>

typedef __bf16 bf16;
typedef __bf16 v8bf __attribute__((ext_vector_type(8)));
typedef float f32x4 __attribute__((ext_vector_type(4)));
typedef float f32x2 __attribute__((ext_vector_type(2)));

#define NN 20000
#define EE 320000
#define FIN 256
#define D1 512
#define DOUT 128
#define ED 26

__device__ __forceinline__ float b2f(bf16 x) { return (float)x; }

__device__ __forceinline__ f32x2 ldbf2v(const bf16* p) {
  unsigned int u;
  __builtin_memcpy(&u, p, 4);
  union { unsigned int i; float f; } lo, hi;
  lo.i = (u & 0xffffu) << 16;
  hi.i = u & 0xffff0000u;
  return (f32x2){lo.f, hi.f};
}

__device__ __forceinline__ f32x2 ldf2v(const float* p) {
  f32x2 t;
  __builtin_memcpy(&t, p, 8);
  return t;
}

template <typename T> __device__ __forceinline__ f32x2 ldx2(const T* p);
template <> __device__ __forceinline__ f32x2 ldx2<bf16>(const bf16* p) { return ldbf2v(p); }
template <> __device__ __forceinline__ f32x2 ldx2<float>(const float* p) { return ldf2v(p); }

// ---------------- small utils ----------------
__global__ void zero_k(int* __restrict__ p, int n) {
  int i = blockIdx.x * 256 + threadIdx.x;
  if (i < n) p[i] = 0;
}

// ---------------- edge_index dtype detect + convert ------------------------
__global__ void detflag_k(const int* __restrict__ ei32, int* __restrict__ flag) {
  int i = blockIdx.x * 256 + threadIdx.x;
  int v = (i < EE) ? ei32[2 * i + 1] : 0;
  unsigned long long b = __ballot(v != 0);
  if ((threadIdx.x & 63) == 0 && b) atomicOr(flag, 1);
}

__global__ void conv_k(const void* __restrict__ ei, const int* __restrict__ flag,
                       int* __restrict__ src, int* __restrict__ dst) {
  int i = blockIdx.x * 256 + threadIdx.x;
  if (i >= EE) return;
  int s, d;
  if (*flag == 0) {
    const long long* p = (const long long*)ei;
    s = (int)p[i];
    d = (int)p[EE + i];
  } else {
    const int* p = (const int*)ei;
    s = p[i];
    d = p[EE + i];
  }
  src[i] = min(max(s, 0), NN - 1);
  dst[i] = min(max(d, 0), NN - 1);
}

// ---------------- CSR build ----------------
__global__ void hist_k(const int* __restrict__ dst, int* __restrict__ deg, int n) {
  int e = blockIdx.x * 256 + threadIdx.x;
  if (e < n) atomicAdd(&deg[dst[e]], 1);
}

__global__ __launch_bounds__(1024) void scan_k(const int* __restrict__ deg,
                                               int* __restrict__ offs,
                                               int* __restrict__ cursor, int n) {
  __shared__ int lsum[1024];
  int t = threadIdx.x;
  const int CH = (n + 1023) / 1024;
  int base = t * CH;
  int s = 0;
  for (int i = 0; i < CH; i++) {
    int idx = base + i;
    if (idx < n) s += deg[idx];
  }
  lsum[t] = s;
  __syncthreads();
  for (int o = 1; o < 1024; o <<= 1) {
    int v = (t >= o) ? lsum[t - o] : 0;
    __syncthreads();
    lsum[t] += v;
    __syncthreads();
  }
  int ex = (t == 0) ? 0 : lsum[t - 1];
  for (int i = 0; i < CH; i++) {
    int idx = base + i;
    if (idx < n) {
      offs[idx] = ex;
      cursor[idx] = ex;
      ex += deg[idx];
    }
  }
  if (t == 1023) offs[n] = lsum[1023];
}

__global__ void scatter_k(const int* __restrict__ dst, int* __restrict__ cursor,
                          int* __restrict__ elist, int n) {
  int e = blockIdx.x * 256 + threadIdx.x;
  if (e < n) {
    int p = atomicAdd(&cursor[dst[e]], 1);
    if ((unsigned)p < (unsigned)EE) elist[p] = e;
  }
}

// ------- MFMA GEMM (round-9 version): out (+)= bf16(A)@bf16(B) + bias ------
template <typename TA, typename TO, bool ADD>
__global__ __launch_bounds__(256) void gemm_t(const TA* __restrict__ A,
                                              const float* __restrict__ B,
                                              const float* __restrict__ bias,
                                              TO* out, int Nc, int K) {
  int w = threadIdx.x >> 6;
  int l = threadIdx.x & 63;
  int quad = l >> 4;
  int mrow = blockIdx.y * 16 + (l & 15);
  int col = blockIdx.x * 64 + w * 16 + (l & 15);
  f32x4 acc = {0.f, 0.f, 0.f, 0.f};
  for (int k0 = 0; k0 < K; k0 += 32) {
    int ka = k0 + quad * 8;
    v8bf a, b;
    if constexpr (sizeof(TA) == 4) {
      const float* ap = (const float*)A + (size_t)mrow * K + ka;
#pragma unroll
      for (int j = 0; j < 8; j++) a[j] = (bf16)ap[j];
    } else {
      __builtin_memcpy(&a, (const bf16*)A + (size_t)mrow * K + ka, 16);
    }
#pragma unroll
    for (int j = 0; j < 8; j++) b[j] = (bf16)B[(size_t)(ka + j) * Nc + col];
    acc = __builtin_amdgcn_mfma_f32_16x16x32_bf16(a, b, acc, 0, 0, 0);
  }
  float bb = bias[col];
  int obase = blockIdx.y * 16 + quad * 4;
#pragma unroll
  for (int r = 0; r < 4; r++) {
    size_t idx = (size_t)(obase + r) * Nc + col;
    float v = acc[r] + bb;
    if (ADD) v += (float)out[idx];
    out[idx] = (TO)v;
  }
}

// ---------------- edge-parallel alpha: alpha[e][h] -------------------------
// grid-stride over edges; wave w = head w; lane owns cols 128w+2l, +1.
// We columns held in 26 NAMED f32x2 registers (arrays were not registerized
// in r8-r10: VGPR stayed 40 and We was re-loaded per edge).
#define WE_DECL(j) f32x2 we##j = ldf2v(We + j * D + c);
#define WE_ALL WE_DECL(0) WE_DECL(1) WE_DECL(2) WE_DECL(3) WE_DECL(4)   \
  WE_DECL(5) WE_DECL(6) WE_DECL(7) WE_DECL(8) WE_DECL(9) WE_DECL(10)   \
  WE_DECL(11) WE_DECL(12) WE_DECL(13) WE_DECL(14) WE_DECL(15)          \
  WE_DECL(16) WE_DECL(17) WE_DECL(18) WE_DECL(19) WE_DECL(20)          \
  WE_DECL(21) WE_DECL(22) WE_DECL(23) WE_DECL(24) WE_DECL(25)
#define EF(p, a, b)                                                     \
  { f32x2 t = ldf2v(ear + 2 * p);                                       \
    et += (f32x2){t.x, t.x} * we##a;                                    \
    et += (f32x2){t.y, t.y} * we##b; }
#define EF_ALL EF(0,0,1) EF(1,2,3) EF(2,4,5) EF(3,6,7) EF(4,8,9)        \
  EF(5,10,11) EF(6,12,13) EF(7,14,15) EF(8,16,17) EF(9,18,19)           \
  EF(10,20,21) EF(11,22,23) EF(12,24,25)

template <int H, typename TX>
__global__ __launch_bounds__(64 * H, 2) void ealpha(
    const TX* __restrict__ xl, const TX* __restrict__ xr,
    const float* __restrict__ eatt, const float* __restrict__ We,
    const float* __restrict__ att, const int* __restrict__ srcs,
    const int* __restrict__ dsts, float* __restrict__ alpha) {
  const int D = 128 * H;
  int tid = threadIdx.x;
  int w = tid >> 6, l = tid & 63;
  int c = w * 128 + 2 * l;
  WE_ALL
  f32x2 av = ldf2v(att + c);
  for (int e = blockIdx.x; e < EE; e += gridDim.x) {
    int s = __builtin_amdgcn_readfirstlane(srcs[e]);
    int d = __builtin_amdgcn_readfirstlane(dsts[e]);
    const float* ear = eatt + (size_t)e * ED;
    f32x2 et = {0.f, 0.f};
    EF_ALL
    f32x2 xv = ldx2<TX>(xl + (size_t)s * D + c);
    f32x2 rv = ldx2<TX>(xr + (size_t)d * D + c);
    f32x2 mm = xv + rv + et;
    f32x2 pos = {fmaxf(mm.x, 0.f), fmaxf(mm.y, 0.f)};
    f32x2 neg = {fminf(mm.x, 0.f), fminf(mm.y, 0.f)};
    mm = pos + 0.2f * neg;                 // leaky_relu
    float al = mm.x * av.x + mm.y * av.y;
#pragma unroll
    for (int o = 32; o; o >>= 1) al += __shfl_xor(al, o, 64);
    if (l == 0) alpha[(size_t)e * H + w] = al;
  }
}

// ---------------- node-parallel fold: segment-softmax + aggregate ----------
// pass1: max over in-edge alphas; pass2: p=exp(a-m), acc += p*xl[src].
template <int H, typename TX, typename TO>
__global__ __launch_bounds__(64 * H) void fold(
    const TX* __restrict__ xl, const float* __restrict__ alpha,
    const float* __restrict__ bias, const int* __restrict__ srcs,
    const int* __restrict__ offs, const int* __restrict__ elist,
    TO* __restrict__ out) {
  const int D = 128 * H;
  int node = blockIdx.x;
  int tid = threadIdx.x;
  int w = tid >> 6, l = tid & 63;
  int c = w * 128 + 2 * l;
  int i0 = offs[node], i1 = offs[node + 1];
  i0 = max(0, min(i0, EE));
  i1 = max(i0, min(i1, EE));
  float m = -3.0e38f;
  for (int i = i0; i < i1; i++) {
    int e = __builtin_amdgcn_readfirstlane(elist[i]);
    m = fmaxf(m, alpha[(size_t)e * H + w]);
  }
  float den = 0.f;
  f32x2 acc = {0.f, 0.f};
  for (int i = i0; i < i1; i++) {
    int e = __builtin_amdgcn_readfirstlane(elist[i]);
    float p = __expf(alpha[(size_t)e * H + w] - m);
    int s = __builtin_amdgcn_readfirstlane(srcs[e]);
    f32x2 xv = ldx2<TX>(xl + (size_t)s * D + c);
    den += p;
    acc += (f32x2){p, p} * xv;
  }
  float inv = 1.f / (den + 1e-16f);
  out[(size_t)node * D + c] = (TO)(acc.x * inv + bias[c]);
  out[(size_t)node * D + c + 1] = (TO)(acc.y * inv + bias[c + 1]);
}

// ---------------- LayerNorm(512) + ELU, in place (bf16) --------------------
__global__ __launch_bounds__(256) void lnelu_k(bf16* buf,
                                               const float* __restrict__ g,
                                               const float* __restrict__ be) {
  int node = blockIdx.x, tid = threadIdx.x;
  int w = tid >> 6, l = tid & 63;
  int c = tid * 2;
  f32x2 o = ldbf2v(buf + (size_t)node * D1 + c);
  float s1 = o.x + o.y, s2 = o.x * o.x + o.y * o.y;
#pragma unroll
  for (int of = 32; of; of >>= 1) {
    s1 += __shfl_xor(s1, of, 64);
    s2 += __shfl_xor(s2, of, 64);
  }
  __shared__ float r1[4], r2[4];
  if (l == 0) { r1[w] = s1; r2[w] = s2; }
  __syncthreads();
  float S1 = r1[0] + r1[1] + r1[2] + r1[3];
  float S2 = r2[0] + r2[1] + r2[2] + r2[3];
  float mu = S1 * (1.f / 512.f);
  float var = fmaxf(S2 * (1.f / 512.f) - mu * mu, 0.f);
  float rs = rsqrtf(var + 1e-5f);
  float y0 = (o.x - mu) * rs * g[c] + be[c];
  float y1 = (o.y - mu) * rs * g[c + 1] + be[c + 1];
  y0 = y0 > 0.f ? y0 : __expf(fminf(y0, 0.f)) - 1.f;
  y1 = y1 > 0.f ? y1 : __expf(fminf(y1, 0.f)) - 1.f;
  buf[(size_t)node * D1 + c] = (bf16)y0;
  buf[(size_t)node * D1 + c + 1] = (bf16)y1;
}

// ---------------- final LayerNorm(128): f32 -> f32 d_out -------------------
__global__ __launch_bounds__(64) void ln128_k(const float* __restrict__ buf,
                                              const float* __restrict__ g,
                                              const float* __restrict__ be,
                                              float* __restrict__ outp) {
  int node = blockIdx.x, l = threadIdx.x;
  int c = 2 * l;
  f32x2 o = ldf2v(buf + (size_t)node * DOUT + c);
  float s1 = o.x + o.y, s2 = o.x * o.x + o.y * o.y;
#pragma unroll
  for (int of = 32; of; of >>= 1) {
    s1 += __shfl_xor(s1, of, 64);
    s2 += __shfl_xor(s2, of, 64);
  }
  float mu = s1 * (1.f / 128.f);
  float var = fmaxf(s2 * (1.f / 128.f) - mu * mu, 0.f);
  float rs = rsqrtf(var + 1e-5f);
  outp[(size_t)node * DOUT + c] = (o.x - mu) * rs * g[c] + be[c];
  outp[(size_t)node * DOUT + c + 1] = (o.y - mu) * rs * g[c + 1] + be[c + 1];
}

extern "C" void kernel_launch(void* const* d_in, const int* in_sizes, int n_in,
                              void* d_out, int out_size, void* d_ws, size_t ws_size,
                              hipStream_t stream) {
  const float* x = (const float*)d_in[0];
  const void* ei = d_in[1];
  const float* eattr = (const float*)d_in[2];
  const float* W1l = (const float*)d_in[3];
  const float* b1l = (const float*)d_in[4];
  const float* W1r = (const float*)d_in[5];
  const float* b1r = (const float*)d_in[6];
  const float* We1 = (const float*)d_in[7];
  const float* att1 = (const float*)d_in[8];
  const float* bias1 = (const float*)d_in[9];
  const float* Wsk1 = (const float*)d_in[10];
  const float* bsk1 = (const float*)d_in[11];
  const float* g1 = (const float*)d_in[12];
  const float* be1 = (const float*)d_in[13];
  const float* W2l = (const float*)d_in[14];
  const float* b2l = (const float*)d_in[15];
  const float* W2r = (const float*)d_in[16];
  const float* b2r = (const float*)d_in[17];
  const float* We2 = (const float*)d_in[18];
  const float* att2 = (const float*)d_in[19];
  const float* bias2 = (const float*)d_in[20];
  const float* Wsk2 = (const float*)d_in[21];
  const float* bsk2 = (const float*)d_in[22];
  const float* g2 = (const float*)d_in[23];
  const float* be2 = (const float*)d_in[24];

  // workspace carve (256B aligned) -- total ~51.6 MiB
  char* p = (char*)d_ws;
  size_t off = 0;
  auto carve = [&](size_t bytes) {
    void* r = p + off;
    off = (off + bytes + 255) & ~(size_t)255;
    return r;
  };
  int* flag = (int*)carve(sizeof(int));
  int* srcD = (int*)carve(EE * sizeof(int));
  int* dstD = (int*)carve(EE * sizeof(int));
  int* deg = (int*)carve(NN * sizeof(int));
  int* offs = (int*)carve((NN + 1) * sizeof(int));
  int* cursor = (int*)carve(NN * sizeof(int));
  int* elist = (int*)carve(EE * sizeof(int));
  float* alph1 = (float*)carve((size_t)EE * 4 * sizeof(float));
  float* alph2 = (float*)carve((size_t)EE * sizeof(float));
  bf16* bufA = (bf16*)carve((size_t)NN * D1 * 2);  // xl1 (bf16); then f32 x2l/x2r
  bf16* bufB = (bf16*)carve((size_t)NN * D1 * 2);  // xr1 -> fold1 out -> h (bf16)

  float* q0 = (float*)bufA;              // x2l (f32)
  float* q1 = q0 + (size_t)NN * DOUT;    // x2r (f32) -> fold2 out

  // edge_index detect + convert
  zero_k<<<1, 256, 0, stream>>>(flag, 1);
  detflag_k<<<(EE + 255) / 256, 256, 0, stream>>>((const int*)ei, flag);
  conv_k<<<(EE + 255) / 256, 256, 0, stream>>>(ei, flag, srcD, dstD);

  // CSR build (by dst)
  zero_k<<<(NN + 255) / 256, 256, 0, stream>>>(deg, NN);
  hist_k<<<(EE + 255) / 256, 256, 0, stream>>>(dstD, deg, EE);
  scan_k<<<1, 1024, 0, stream>>>(deg, offs, cursor, NN);
  scatter_k<<<(EE + 255) / 256, 256, 0, stream>>>(dstD, cursor, elist, EE);

  // layer-1: xl = x@W1l+b1l, xr = x@W1r+b1r  (f32 A, bf16 out)
  gemm_t<float, bf16, false><<<dim3(D1 / 64, NN / 16), 256, 0, stream>>>(x, W1l, b1l, bufA, D1, FIN);
  gemm_t<float, bf16, false><<<dim3(D1 / 64, NN / 16), 256, 0, stream>>>(x, W1r, b1r, bufB, D1, FIN);
  // edge-parallel alpha, then node-parallel softmax+aggregate (+bias1)
  ealpha<4, bf16><<<2048, 256, 0, stream>>>(bufA, bufB, eattr, We1, att1,
                                            srcD, dstD, alph1);
  fold<4, bf16, bf16><<<NN, 256, 0, stream>>>(bufA, alph1, bias1, srcD,
                                              offs, elist, bufB);
  // += x@Wskip1 + bskip1
  gemm_t<float, bf16, true><<<dim3(D1 / 64, NN / 16), 256, 0, stream>>>(x, Wsk1, bsk1, bufB, D1, FIN);
  lnelu_k<<<NN, 256, 0, stream>>>(bufB, g1, be1);

  // layer-2: x2l = h@W2l+b2l, x2r = h@W2r+b2r  (bf16 A, f32 out)
  gemm_t<bf16, float, false><<<dim3(DOUT / 64, NN / 16), 256, 0, stream>>>(bufB, W2l, b2l, q0, DOUT, D1);
  gemm_t<bf16, float, false><<<dim3(DOUT / 64, NN / 16), 256, 0, stream>>>(bufB, W2r, b2r, q1, DOUT, D1);
  ealpha<1, float><<<2048, 64, 0, stream>>>(q0, q1, eattr, We2, att2,
                                            srcD, dstD, alph2);
  fold<1, float, float><<<NN, 64, 0, stream>>>(q0, alph2, bias2, srcD,
                                               offs, elist, q1);
  gemm_t<bf16, float, true><<<dim3(DOUT / 64, NN / 16), 256, 0, stream>>>(bufB, Wsk2, bsk2, q1, DOUT, D1);
  ln128_k<<<NN, 64, 0, stream>>>(q1, g2, be2, (float*)d_out);

  (void)in_sizes; (void)n_in; (void)out_size; (void)ws_size;
}

// Round 12
// 963.867 us; speedup vs baseline: 1.3717x; 1.3717x over previous
//
#include <hip/hip_runtime.h>
#include <hip/hip_bf16.h>

typedef __bf16 bf16;
typedef __bf16 v8bf __attribute__((ext_vector_type(8)));
typedef float f32x4 __attribute__((ext_vector_type(4)));
typedef float f32x2 __attribute__((ext_vector_type(2)));

#define NN 20000
#define EE 320000
#define FIN 256
#define D1 512
#define DOUT 128
#define ED 26

__device__ __forceinline__ float b2f(bf16 x) { return (float)x; }

__device__ __forceinline__ f32x2 ldbf2v(const bf16* p) {
  unsigned int u;
  __builtin_memcpy(&u, p, 4);
  union { unsigned int i; float f; } lo, hi;
  lo.i = (u & 0xffffu) << 16;
  hi.i = u & 0xffff0000u;
  return (f32x2){lo.f, hi.f};
}

__device__ __forceinline__ f32x2 ldf2v(const float* p) {
  f32x2 t;
  __builtin_memcpy(&t, p, 8);
  return t;
}

// ---------------- small utils ----------------
__global__ void zero_k(int* __restrict__ p, int n) {
  int i = blockIdx.x * 256 + threadIdx.x;
  if (i < n) p[i] = 0;
}

// ---------------- edge_index dtype detect + convert ------------------------
__global__ void detflag_k(const int* __restrict__ ei32, int* __restrict__ flag) {
  int i = blockIdx.x * 256 + threadIdx.x;
  int v = (i < EE) ? ei32[2 * i + 1] : 0;
  unsigned long long b = __ballot(v != 0);
  if ((threadIdx.x & 63) == 0 && b) atomicOr(flag, 1);
}

__global__ void conv_k(const void* __restrict__ ei, const int* __restrict__ flag,
                       int* __restrict__ src, int* __restrict__ dst) {
  int i = blockIdx.x * 256 + threadIdx.x;
  if (i >= EE) return;
  int s, d;
  if (*flag == 0) {
    const long long* p = (const long long*)ei;
    s = (int)p[i];
    d = (int)p[EE + i];
  } else {
    const int* p = (const int*)ei;
    s = p[i];
    d = p[EE + i];
  }
  src[i] = min(max(s, 0), NN - 1);
  dst[i] = min(max(d, 0), NN - 1);
}

// ---------------- CSR build ----------------
__global__ void hist_k(const int* __restrict__ dst, int* __restrict__ deg, int n) {
  int e = blockIdx.x * 256 + threadIdx.x;
  if (e < n) atomicAdd(&deg[dst[e]], 1);
}

__global__ __launch_bounds__(1024) void scan_k(const int* __restrict__ deg,
                                               int* __restrict__ offs,
                                               int* __restrict__ cursor, int n) {
  __shared__ int lsum[1024];
  int t = threadIdx.x;
  const int CH = (n + 1023) / 1024;
  int base = t * CH;
  int s = 0;
  for (int i = 0; i < CH; i++) {
    int idx = base + i;
    if (idx < n) s += deg[idx];
  }
  lsum[t] = s;
  __syncthreads();
  for (int o = 1; o < 1024; o <<= 1) {
    int v = (t >= o) ? lsum[t - o] : 0;
    __syncthreads();
    lsum[t] += v;
    __syncthreads();
  }
  int ex = (t == 0) ? 0 : lsum[t - 1];
  for (int i = 0; i < CH; i++) {
    int idx = base + i;
    if (idx < n) {
      offs[idx] = ex;
      cursor[idx] = ex;
      ex += deg[idx];
    }
  }
  if (t == 1023) offs[n] = lsum[1023];
}

__global__ void scatter_k(const int* __restrict__ dst, int* __restrict__ cursor,
                          int* __restrict__ elist, int n) {
  int e = blockIdx.x * 256 + threadIdx.x;
  if (e < n) {
    int p = atomicAdd(&cursor[dst[e]], 1);
    if ((unsigned)p < (unsigned)EE) elist[p] = e;
  }
}

// ------- MFMA GEMM (single-output, for skip ADD): out (+)= A@B + bias ------
template <typename TA, typename TO, bool ADD>
__global__ __launch_bounds__(256) void gemm_t(const TA* __restrict__ A,
                                              const float* __restrict__ B,
                                              const float* __restrict__ bias,
                                              TO* out, int Nc, int K) {
  int w = threadIdx.x >> 6;
  int l = threadIdx.x & 63;
  int quad = l >> 4;
  int mrow = blockIdx.y * 16 + (l & 15);
  int col = blockIdx.x * 64 + w * 16 + (l & 15);
  f32x4 acc = {0.f, 0.f, 0.f, 0.f};
  for (int k0 = 0; k0 < K; k0 += 32) {
    int ka = k0 + quad * 8;
    v8bf a, b;
    if constexpr (sizeof(TA) == 4) {
      const float* ap = (const float*)A + (size_t)mrow * K + ka;
#pragma unroll
      for (int j = 0; j < 8; j++) a[j] = (bf16)ap[j];
    } else {
      __builtin_memcpy(&a, (const bf16*)A + (size_t)mrow * K + ka, 16);
    }
#pragma unroll
    for (int j = 0; j < 8; j++) b[j] = (bf16)B[(size_t)(ka + j) * Nc + col];
    acc = __builtin_amdgcn_mfma_f32_16x16x32_bf16(a, b, acc, 0, 0, 0);
  }
  float bb = bias[col];
  int obase = blockIdx.y * 16 + quad * 4;
#pragma unroll
  for (int r = 0; r < 4; r++) {
    size_t idx = (size_t)(obase + r) * Nc + col;
    float v = acc[r] + bb;
    if (ADD) v += (float)out[idx];
    out[idx] = (TO)v;
  }
}

// ------- 2-output fused MFMA GEMM: shares the A fragment across B0/B1 ------
template <typename TA, typename TO>
__global__ __launch_bounds__(256) void gemm2_t(const TA* __restrict__ A,
                                               const float* __restrict__ B0,
                                               const float* __restrict__ B1,
                                               const float* __restrict__ bias0,
                                               const float* __restrict__ bias1,
                                               TO* __restrict__ out0,
                                               TO* __restrict__ out1,
                                               int Nc, int K) {
  int w = threadIdx.x >> 6;
  int l = threadIdx.x & 63;
  int quad = l >> 4;
  int mrow = blockIdx.y * 16 + (l & 15);
  int col = blockIdx.x * 64 + w * 16 + (l & 15);
  f32x4 acc0 = {0.f, 0.f, 0.f, 0.f};
  f32x4 acc1 = {0.f, 0.f, 0.f, 0.f};
  for (int k0 = 0; k0 < K; k0 += 32) {
    int ka = k0 + quad * 8;
    v8bf a, b0, b1;
    if constexpr (sizeof(TA) == 4) {
      const float* ap = (const float*)A + (size_t)mrow * K + ka;
#pragma unroll
      for (int j = 0; j < 8; j++) a[j] = (bf16)ap[j];
    } else {
      __builtin_memcpy(&a, (const bf16*)A + (size_t)mrow * K + ka, 16);
    }
#pragma unroll
    for (int j = 0; j < 8; j++) {
      size_t bi = (size_t)(ka + j) * Nc + col;
      b0[j] = (bf16)B0[bi];
      b1[j] = (bf16)B1[bi];
    }
    acc0 = __builtin_amdgcn_mfma_f32_16x16x32_bf16(a, b0, acc0, 0, 0, 0);
    acc1 = __builtin_amdgcn_mfma_f32_16x16x32_bf16(a, b1, acc1, 0, 0, 0);
  }
  float bb0 = bias0[col], bb1 = bias1[col];
  int obase = blockIdx.y * 16 + quad * 4;
#pragma unroll
  for (int r = 0; r < 4; r++) {
    size_t idx = (size_t)(obase + r) * Nc + col;
    out0[idx] = (TO)(acc0[r] + bb0);
    out1[idx] = (TO)(acc1[r] + bb1);
  }
}

// ---------------- Layer-1 GATv2 aggregate (+bias), bf16 features ----------
// grid: NN x 256; wave w = head w; lane owns cols 128w+2l, +1.
// Packed f32x2 math (r10, 277us) + (e,s) index prefetch to break the
// elist->srcs->xl dependent-load chain. hout may alias xr.
__global__ __launch_bounds__(256) void l1_agg(
    const bf16* __restrict__ xl, const bf16* xr,
    const float* __restrict__ eatt, const float* __restrict__ We,
    const float* __restrict__ att, const float* __restrict__ bias,
    const int* __restrict__ srcs, const int* __restrict__ offs,
    const int* __restrict__ elist, bf16* hout) {
  int node = blockIdx.x;
  int tid = threadIdx.x;
  int w = tid >> 6, l = tid & 63;
  int c = w * 128 + 2 * l;

  f32x2 we[ED];
#pragma unroll
  for (int j = 0; j < ED; j++) {
    we[j] = (f32x2){We[(size_t)j * D1 + c], We[(size_t)j * D1 + c + 1]};
  }
  f32x2 av = ldf2v(att + c);
  f32x2 rv = ldbf2v(xr + (size_t)node * D1 + c);

  float m = -3.0e38f, den = 0.f;
  f32x2 acc = {0.f, 0.f};
  int i0 = offs[node], i1 = offs[node + 1];
  i0 = max(0, min(i0, EE));
  i1 = max(i0, min(i1, EE));
  int e = 0, s = 0;
  if (i0 < i1) {
    e = __builtin_amdgcn_readfirstlane(elist[i0]);
    s = __builtin_amdgcn_readfirstlane(srcs[e]);
  }
  for (int i = i0; i < i1; i++) {
    int e_n = e, s_n = s;
    if (i + 1 < i1) {                       // prefetch next edge's indices
      e_n = __builtin_amdgcn_readfirstlane(elist[i + 1]);
      s_n = __builtin_amdgcn_readfirstlane(srcs[e_n]);
    }
    f32x2 xv = ldbf2v(xl + (size_t)s * D1 + c);   // issue gather early
    const float* ear = eatt + (size_t)e * ED;
    f32x2 et = {0.f, 0.f};
#pragma unroll
    for (int j = 0; j < ED; j += 2) {
      f32x2 t = ldf2v(ear + j);
      et += (f32x2){t.x, t.x} * we[j];
      et += (f32x2){t.y, t.y} * we[j + 1];
    }
    f32x2 mm = xv + rv + et;
    f32x2 pos = {fmaxf(mm.x, 0.f), fmaxf(mm.y, 0.f)};
    f32x2 neg = {fminf(mm.x, 0.f), fminf(mm.y, 0.f)};
    mm = pos + 0.2f * neg;                 // leaky_relu
    float al = mm.x * av.x + mm.y * av.y;
#pragma unroll
    for (int o = 32; o; o >>= 1) al += __shfl_xor(al, o, 64);
    float nm = fmaxf(m, al);
    float sc = __expf(m - nm);
    float pr = __expf(al - nm);
    den = den * sc + pr;
    acc = acc * sc + (f32x2){pr, pr} * xv;
    m = nm;
    e = e_n;
    s = s_n;
  }
  float inv = 1.f / (den + 1e-16f);
  hout[(size_t)node * D1 + c] = (bf16)(acc.x * inv + bias[c]);
  hout[(size_t)node * D1 + c + 1] = (bf16)(acc.y * inv + bias[c + 1]);
}

// ---------------- Layer-2 GATv2 aggregate (+bias), 1 head, f32 features ---
// 4 nodes per block (wave w = node), lane owns cols 2l, 2l+1. Prefetched.
__global__ __launch_bounds__(256) void l2_agg(
    const float* __restrict__ xl, const float* xr,
    const float* __restrict__ eatt, const float* __restrict__ We,
    const float* __restrict__ att, const float* __restrict__ bias,
    const int* __restrict__ srcs, const int* __restrict__ offs,
    const int* __restrict__ elist, float* hout) {
  int tid = threadIdx.x;
  int w = tid >> 6, l = tid & 63;
  int node = blockIdx.x * 4 + w;
  if (node >= NN) return;
  int c = 2 * l;
  f32x2 we[ED];
#pragma unroll
  for (int j = 0; j < ED; j++) {
    we[j] = (f32x2){We[(size_t)j * DOUT + c], We[(size_t)j * DOUT + c + 1]};
  }
  f32x2 av = ldf2v(att + c);
  f32x2 rv = ldf2v(xr + (size_t)node * DOUT + c);
  float m = -3.0e38f, den = 0.f;
  f32x2 acc = {0.f, 0.f};
  int i0 = offs[node], i1 = offs[node + 1];
  i0 = max(0, min(i0, EE));
  i1 = max(i0, min(i1, EE));
  int e = 0, s = 0;
  if (i0 < i1) {
    e = __builtin_amdgcn_readfirstlane(elist[i0]);
    s = __builtin_amdgcn_readfirstlane(srcs[e]);
  }
  for (int i = i0; i < i1; i++) {
    int e_n = e, s_n = s;
    if (i + 1 < i1) {
      e_n = __builtin_amdgcn_readfirstlane(elist[i + 1]);
      s_n = __builtin_amdgcn_readfirstlane(srcs[e_n]);
    }
    f32x2 xv = ldf2v(xl + (size_t)s * DOUT + c);
    const float* ear = eatt + (size_t)e * ED;
    f32x2 et = {0.f, 0.f};
#pragma unroll
    for (int j = 0; j < ED; j += 2) {
      f32x2 t = ldf2v(ear + j);
      et += (f32x2){t.x, t.x} * we[j];
      et += (f32x2){t.y, t.y} * we[j + 1];
    }
    f32x2 mm = xv + rv + et;
    f32x2 pos = {fmaxf(mm.x, 0.f), fmaxf(mm.y, 0.f)};
    f32x2 neg = {fminf(mm.x, 0.f), fminf(mm.y, 0.f)};
    mm = pos + 0.2f * neg;
    float al = mm.x * av.x + mm.y * av.y;
#pragma unroll
    for (int o = 32; o; o >>= 1) al += __shfl_xor(al, o, 64);
    float nm = fmaxf(m, al);
    float sc = __expf(m - nm);
    float pr = __expf(al - nm);
    den = den * sc + pr;
    acc = acc * sc + (f32x2){pr, pr} * xv;
    m = nm;
    e = e_n;
    s = s_n;
  }
  float inv = 1.f / (den + 1e-16f);
  hout[(size_t)node * DOUT + c] = acc.x * inv + bias[c];
  hout[(size_t)node * DOUT + c + 1] = acc.y * inv + bias[c + 1];
}

// ---------------- LayerNorm(512) + ELU, in place (bf16) --------------------
__global__ __launch_bounds__(256) void lnelu_k(bf16* buf,
                                               const float* __restrict__ g,
                                               const float* __restrict__ be) {
  int node = blockIdx.x, tid = threadIdx.x;
  int w = tid >> 6, l = tid & 63;
  int c = tid * 2;
  f32x2 o = ldbf2v(buf + (size_t)node * D1 + c);
  float s1 = o.x + o.y, s2 = o.x * o.x + o.y * o.y;
#pragma unroll
  for (int of = 32; of; of >>= 1) {
    s1 += __shfl_xor(s1, of, 64);
    s2 += __shfl_xor(s2, of, 64);
  }
  __shared__ float r1[4], r2[4];
  if (l == 0) { r1[w] = s1; r2[w] = s2; }
  __syncthreads();
  float S1 = r1[0] + r1[1] + r1[2] + r1[3];
  float S2 = r2[0] + r2[1] + r2[2] + r2[3];
  float mu = S1 * (1.f / 512.f);
  float var = fmaxf(S2 * (1.f / 512.f) - mu * mu, 0.f);
  float rs = rsqrtf(var + 1e-5f);
  float y0 = (o.x - mu) * rs * g[c] + be[c];
  float y1 = (o.y - mu) * rs * g[c + 1] + be[c + 1];
  y0 = y0 > 0.f ? y0 : __expf(fminf(y0, 0.f)) - 1.f;
  y1 = y1 > 0.f ? y1 : __expf(fminf(y1, 0.f)) - 1.f;
  buf[(size_t)node * D1 + c] = (bf16)y0;
  buf[(size_t)node * D1 + c + 1] = (bf16)y1;
}

// ---------------- final LayerNorm(128): 4 nodes/block, f32 -> d_out --------
__global__ __launch_bounds__(256) void ln128_k(const float* __restrict__ buf,
                                               const float* __restrict__ g,
                                               const float* __restrict__ be,
                                               float* __restrict__ outp) {
  int tid = threadIdx.x;
  int w = tid >> 6, l = tid & 63;
  int node = blockIdx.x * 4 + w;
  if (node >= NN) return;
  int c = 2 * l;
  f32x2 o = ldf2v(buf + (size_t)node * DOUT + c);
  float s1 = o.x + o.y, s2 = o.x * o.x + o.y * o.y;
#pragma unroll
  for (int of = 32; of; of >>= 1) {
    s1 += __shfl_xor(s1, of, 64);
    s2 += __shfl_xor(s2, of, 64);
  }
  float mu = s1 * (1.f / 128.f);
  float var = fmaxf(s2 * (1.f / 128.f) - mu * mu, 0.f);
  float rs = rsqrtf(var + 1e-5f);
  outp[(size_t)node * DOUT + c] = (o.x - mu) * rs * g[c] + be[c];
  outp[(size_t)node * DOUT + c + 1] = (o.y - mu) * rs * g[c + 1] + be[c + 1];
}

extern "C" void kernel_launch(void* const* d_in, const int* in_sizes, int n_in,
                              void* d_out, int out_size, void* d_ws, size_t ws_size,
                              hipStream_t stream) {
  const float* x = (const float*)d_in[0];
  const void* ei = d_in[1];
  const float* eattr = (const float*)d_in[2];
  const float* W1l = (const float*)d_in[3];
  const float* b1l = (const float*)d_in[4];
  const float* W1r = (const float*)d_in[5];
  const float* b1r = (const float*)d_in[6];
  const float* We1 = (const float*)d_in[7];
  const float* att1 = (const float*)d_in[8];
  const float* bias1 = (const float*)d_in[9];
  const float* Wsk1 = (const float*)d_in[10];
  const float* bsk1 = (const float*)d_in[11];
  const float* g1 = (const float*)d_in[12];
  const float* be1 = (const float*)d_in[13];
  const float* W2l = (const float*)d_in[14];
  const float* b2l = (const float*)d_in[15];
  const float* W2r = (const float*)d_in[16];
  const float* b2r = (const float*)d_in[17];
  const float* We2 = (const float*)d_in[18];
  const float* att2 = (const float*)d_in[19];
  const float* bias2 = (const float*)d_in[20];
  const float* Wsk2 = (const float*)d_in[21];
  const float* bsk2 = (const float*)d_in[22];
  const float* g2 = (const float*)d_in[23];
  const float* be2 = (const float*)d_in[24];

  // workspace carve (256B aligned) -- ~45 MiB (r9-proven layout)
  char* p = (char*)d_ws;
  size_t off = 0;
  auto carve = [&](size_t bytes) {
    void* r = p + off;
    off = (off + bytes + 255) & ~(size_t)255;
    return r;
  };
  int* flag = (int*)carve(sizeof(int));
  int* srcD = (int*)carve(EE * sizeof(int));
  int* dstD = (int*)carve(EE * sizeof(int));
  int* deg = (int*)carve(NN * sizeof(int));
  int* offs = (int*)carve((NN + 1) * sizeof(int));
  int* cursor = (int*)carve(NN * sizeof(int));
  int* elist = (int*)carve(EE * sizeof(int));
  bf16* bufA = (bf16*)carve((size_t)NN * D1 * 2);  // xl1 (bf16); then f32 x2l/x2r
  bf16* bufB = (bf16*)carve((size_t)NN * D1 * 2);  // xr1 -> agg -> +skip -> h

  float* q0 = (float*)bufA;              // x2l (f32)
  float* q1 = q0 + (size_t)NN * DOUT;    // x2r (f32) -> agg2 -> +skip2

  // edge_index detect + convert
  zero_k<<<1, 256, 0, stream>>>(flag, 1);
  detflag_k<<<(EE + 255) / 256, 256, 0, stream>>>((const int*)ei, flag);
  conv_k<<<(EE + 255) / 256, 256, 0, stream>>>(ei, flag, srcD, dstD);

  // CSR build (by dst)
  zero_k<<<(NN + 255) / 256, 256, 0, stream>>>(deg, NN);
  hist_k<<<(EE + 255) / 256, 256, 0, stream>>>(dstD, deg, EE);
  scan_k<<<1, 1024, 0, stream>>>(deg, offs, cursor, NN);
  scatter_k<<<(EE + 255) / 256, 256, 0, stream>>>(dstD, cursor, elist, EE);

  // layer-1: fused (xl, xr) = x @ (W1l, W1r) + (b1l, b1r)
  gemm2_t<float, bf16><<<dim3(D1 / 64, NN / 16), 256, 0, stream>>>(
      x, W1l, W1r, b1l, b1r, bufA, bufB, D1, FIN);
  l1_agg<<<NN, 256, 0, stream>>>(bufA, bufB, eattr, We1, att1, bias1,
                                 srcD, offs, elist, bufB);
  gemm_t<float, bf16, true><<<dim3(D1 / 64, NN / 16), 256, 0, stream>>>(
      x, Wsk1, bsk1, bufB, D1, FIN);
  lnelu_k<<<NN, 256, 0, stream>>>(bufB, g1, be1);

  // layer-2: fused (x2l, x2r) = h @ (W2l, W2r) + (b2l, b2r)  (f32 out)
  gemm2_t<bf16, float><<<dim3(DOUT / 64, NN / 16), 256, 0, stream>>>(
      bufB, W2l, W2r, b2l, b2r, q0, q1, DOUT, D1);
  l2_agg<<<(NN + 3) / 4, 256, 0, stream>>>(q0, q1, eattr, We2, att2, bias2,
                                           srcD, offs, elist, q1);
  gemm_t<bf16, float, true><<<dim3(DOUT / 64, NN / 16), 256, 0, stream>>>(
      bufB, Wsk2, bsk2, q1, DOUT, D1);
  ln128_k<<<(NN + 3) / 4, 256, 0, stream>>>(q1, g2, be2, (float*)d_out);

  (void)in_sizes; (void)n_in; (void)out_size; (void)ws_size;
}

// Round 13
// 876.206 us; speedup vs baseline: 1.5089x; 1.1000x over previous
//
#include <hip/hip_runtime.h>
#include <hip/hip_bf16.h>

typedef __bf16 bf16;
typedef __bf16 v8bf __attribute__((ext_vector_type(8)));
typedef float f32x4 __attribute__((ext_vector_type(4)));
typedef float f32x2 __attribute__((ext_vector_type(2)));

#define NN 20000
#define EE 320000
#define FIN 256
#define D1 512
#define DOUT 128
#define ED 26

__device__ __forceinline__ float b2f(bf16 x) { return (float)x; }

__device__ __forceinline__ f32x2 ldbf2v(const bf16* p) {
  unsigned int u;
  __builtin_memcpy(&u, p, 4);
  union { unsigned int i; float f; } lo, hi;
  lo.i = (u & 0xffffu) << 16;
  hi.i = u & 0xffff0000u;
  return (f32x2){lo.f, hi.f};
}

__device__ __forceinline__ f32x2 ldf2v(const float* p) {
  f32x2 t;
  __builtin_memcpy(&t, p, 8);
  return t;
}

// ---------------- small utils ----------------
__global__ void zero_k(int* __restrict__ p, int n) {
  int i = blockIdx.x * 256 + threadIdx.x;
  if (i < n) p[i] = 0;
}

// ---------------- edge_index dtype detect + convert ------------------------
__global__ void detflag_k(const int* __restrict__ ei32, int* __restrict__ flag) {
  int i = blockIdx.x * 256 + threadIdx.x;
  int v = (i < EE) ? ei32[2 * i + 1] : 0;
  unsigned long long b = __ballot(v != 0);
  if ((threadIdx.x & 63) == 0 && b) atomicOr(flag, 1);
}

__global__ void conv_k(const void* __restrict__ ei, const int* __restrict__ flag,
                       int* __restrict__ src, int* __restrict__ dst) {
  int i = blockIdx.x * 256 + threadIdx.x;
  if (i >= EE) return;
  int s, d;
  if (*flag == 0) {
    const long long* p = (const long long*)ei;
    s = (int)p[i];
    d = (int)p[EE + i];
  } else {
    const int* p = (const int*)ei;
    s = p[i];
    d = p[EE + i];
  }
  src[i] = min(max(s, 0), NN - 1);
  dst[i] = min(max(d, 0), NN - 1);
}

// ---------------- CSR build ----------------
__global__ void hist_k(const int* __restrict__ dst, int* __restrict__ deg, int n) {
  int e = blockIdx.x * 256 + threadIdx.x;
  if (e < n) atomicAdd(&deg[dst[e]], 1);
}

__global__ __launch_bounds__(1024) void scan_k(const int* __restrict__ deg,
                                               int* __restrict__ offs,
                                               int* __restrict__ cursor, int n) {
  __shared__ int lsum[1024];
  int t = threadIdx.x;
  const int CH = (n + 1023) / 1024;
  int base = t * CH;
  int s = 0;
  for (int i = 0; i < CH; i++) {
    int idx = base + i;
    if (idx < n) s += deg[idx];
  }
  lsum[t] = s;
  __syncthreads();
  for (int o = 1; o < 1024; o <<= 1) {
    int v = (t >= o) ? lsum[t - o] : 0;
    __syncthreads();
    lsum[t] += v;
    __syncthreads();
  }
  int ex = (t == 0) ? 0 : lsum[t - 1];
  for (int i = 0; i < CH; i++) {
    int idx = base + i;
    if (idx < n) {
      offs[idx] = ex;
      cursor[idx] = ex;
      ex += deg[idx];
    }
  }
  if (t == 1023) offs[n] = lsum[1023];
}

__global__ void scatter_k(const int* __restrict__ dst, int* __restrict__ cursor,
                          int* __restrict__ elist, int n) {
  int e = blockIdx.x * 256 + threadIdx.x;
  if (e < n) {
    int p = atomicAdd(&cursor[dst[e]], 1);
    if ((unsigned)p < (unsigned)EE) elist[p] = e;
  }
}

// ------- MFMA GEMM (single-output, for fallback skip ADD) ------------------
template <typename TA, typename TO, bool ADD>
__global__ __launch_bounds__(256) void gemm_t(const TA* __restrict__ A,
                                              const float* __restrict__ B,
                                              const float* __restrict__ bias,
                                              TO* out, int Nc, int K) {
  int w = threadIdx.x >> 6;
  int l = threadIdx.x & 63;
  int quad = l >> 4;
  int mrow = blockIdx.y * 16 + (l & 15);
  int col = blockIdx.x * 64 + w * 16 + (l & 15);
  f32x4 acc = {0.f, 0.f, 0.f, 0.f};
  for (int k0 = 0; k0 < K; k0 += 32) {
    int ka = k0 + quad * 8;
    v8bf a, b;
    if constexpr (sizeof(TA) == 4) {
      const float* ap = (const float*)A + (size_t)mrow * K + ka;
#pragma unroll
      for (int j = 0; j < 8; j++) a[j] = (bf16)ap[j];
    } else {
      __builtin_memcpy(&a, (const bf16*)A + (size_t)mrow * K + ka, 16);
    }
#pragma unroll
    for (int j = 0; j < 8; j++) b[j] = (bf16)B[(size_t)(ka + j) * Nc + col];
    acc = __builtin_amdgcn_mfma_f32_16x16x32_bf16(a, b, acc, 0, 0, 0);
  }
  float bb = bias[col];
  int obase = blockIdx.y * 16 + quad * 4;
#pragma unroll
  for (int r = 0; r < 4; r++) {
    size_t idx = (size_t)(obase + r) * Nc + col;
    float v = acc[r] + bb;
    if (ADD) v += (float)out[idx];
    out[idx] = (TO)v;
  }
}

// ------- 2-output fused MFMA GEMM (fallback path) --------------------------
template <typename TA, typename TO>
__global__ __launch_bounds__(256) void gemm2_t(const TA* __restrict__ A,
                                               const float* __restrict__ B0,
                                               const float* __restrict__ B1,
                                               const float* __restrict__ bias0,
                                               const float* __restrict__ bias1,
                                               TO* __restrict__ out0,
                                               TO* __restrict__ out1,
                                               int Nc, int K) {
  int w = threadIdx.x >> 6;
  int l = threadIdx.x & 63;
  int quad = l >> 4;
  int mrow = blockIdx.y * 16 + (l & 15);
  int col = blockIdx.x * 64 + w * 16 + (l & 15);
  f32x4 acc0 = {0.f, 0.f, 0.f, 0.f};
  f32x4 acc1 = {0.f, 0.f, 0.f, 0.f};
  for (int k0 = 0; k0 < K; k0 += 32) {
    int ka = k0 + quad * 8;
    v8bf a, b0, b1;
    if constexpr (sizeof(TA) == 4) {
      const float* ap = (const float*)A + (size_t)mrow * K + ka;
#pragma unroll
      for (int j = 0; j < 8; j++) a[j] = (bf16)ap[j];
    } else {
      __builtin_memcpy(&a, (const bf16*)A + (size_t)mrow * K + ka, 16);
    }
#pragma unroll
    for (int j = 0; j < 8; j++) {
      size_t bi = (size_t)(ka + j) * Nc + col;
      b0[j] = (bf16)B0[bi];
      b1[j] = (bf16)B1[bi];
    }
    acc0 = __builtin_amdgcn_mfma_f32_16x16x32_bf16(a, b0, acc0, 0, 0, 0);
    acc1 = __builtin_amdgcn_mfma_f32_16x16x32_bf16(a, b1, acc1, 0, 0, 0);
  }
  float bb0 = bias0[col], bb1 = bias1[col];
  int obase = blockIdx.y * 16 + quad * 4;
#pragma unroll
  for (int r = 0; r < 4; r++) {
    size_t idx = (size_t)(obase + r) * Nc + col;
    out0[idx] = (TO)(acc0[r] + bb0);
    out1[idx] = (TO)(acc1[r] + bb1);
  }
}

// ------- 3-output fused MFMA GEMM: xl, xr, skip share the A pass -----------
template <typename TA, typename TO>
__global__ __launch_bounds__(256) void gemm3_t(const TA* __restrict__ A,
                                               const float* __restrict__ B0,
                                               const float* __restrict__ B1,
                                               const float* __restrict__ B2,
                                               const float* __restrict__ bias0,
                                               const float* __restrict__ bias1,
                                               const float* __restrict__ bias2,
                                               TO* __restrict__ out0,
                                               TO* __restrict__ out1,
                                               TO* __restrict__ out2,
                                               int Nc, int K) {
  int w = threadIdx.x >> 6;
  int l = threadIdx.x & 63;
  int quad = l >> 4;
  int mrow = blockIdx.y * 16 + (l & 15);
  int col = blockIdx.x * 64 + w * 16 + (l & 15);
  f32x4 acc0 = {0.f, 0.f, 0.f, 0.f};
  f32x4 acc1 = {0.f, 0.f, 0.f, 0.f};
  f32x4 acc2 = {0.f, 0.f, 0.f, 0.f};
  for (int k0 = 0; k0 < K; k0 += 32) {
    int ka = k0 + quad * 8;
    v8bf a, b0, b1, b2;
    if constexpr (sizeof(TA) == 4) {
      const float* ap = (const float*)A + (size_t)mrow * K + ka;
#pragma unroll
      for (int j = 0; j < 8; j++) a[j] = (bf16)ap[j];
    } else {
      __builtin_memcpy(&a, (const bf16*)A + (size_t)mrow * K + ka, 16);
    }
#pragma unroll
    for (int j = 0; j < 8; j++) {
      size_t bi = (size_t)(ka + j) * Nc + col;
      b0[j] = (bf16)B0[bi];
      b1[j] = (bf16)B1[bi];
      b2[j] = (bf16)B2[bi];
    }
    acc0 = __builtin_amdgcn_mfma_f32_16x16x32_bf16(a, b0, acc0, 0, 0, 0);
    acc1 = __builtin_amdgcn_mfma_f32_16x16x32_bf16(a, b1, acc1, 0, 0, 0);
    acc2 = __builtin_amdgcn_mfma_f32_16x16x32_bf16(a, b2, acc2, 0, 0, 0);
  }
  float bb0 = bias0[col], bb1 = bias1[col], bb2 = bias2[col];
  int obase = blockIdx.y * 16 + quad * 4;
#pragma unroll
  for (int r = 0; r < 4; r++) {
    size_t idx = (size_t)(obase + r) * Nc + col;
    out0[idx] = (TO)(acc0[r] + bb0);
    out1[idx] = (TO)(acc1[r] + bb1);
    out2[idx] = (TO)(acc2[r] + bb2);
  }
}

// ---- Layer-1 FUSED: GATv2 aggregate + bias + skip + LayerNorm + ELU -------
// grid: NN x 256; wave w = head w; lane owns cols 128w+2l, +1.
// hout may alias xr (own-row read before write). skip is a separate buffer.
__global__ __launch_bounds__(256) void l1_agg_f(
    const bf16* __restrict__ xl, const bf16* xr,
    const bf16* __restrict__ skip, const float* __restrict__ eatt,
    const float* __restrict__ We, const float* __restrict__ att,
    const float* __restrict__ bias, const float* __restrict__ g,
    const float* __restrict__ be, const int* __restrict__ srcs,
    const int* __restrict__ offs, const int* __restrict__ elist,
    bf16* hout) {
  int node = blockIdx.x;
  int tid = threadIdx.x;
  int w = tid >> 6, l = tid & 63;
  int c = w * 128 + 2 * l;

  f32x2 we[ED];
#pragma unroll
  for (int j = 0; j < ED; j++) {
    we[j] = (f32x2){We[(size_t)j * D1 + c], We[(size_t)j * D1 + c + 1]};
  }
  f32x2 av = ldf2v(att + c);
  f32x2 rv = ldbf2v(xr + (size_t)node * D1 + c);

  float m = -3.0e38f, den = 0.f;
  f32x2 acc = {0.f, 0.f};
  int i0 = offs[node], i1 = offs[node + 1];
  i0 = max(0, min(i0, EE));
  i1 = max(i0, min(i1, EE));
  int e = 0, s = 0;
  if (i0 < i1) {
    e = __builtin_amdgcn_readfirstlane(elist[i0]);
    s = __builtin_amdgcn_readfirstlane(srcs[e]);
  }
  for (int i = i0; i < i1; i++) {
    int e_n = e, s_n = s;
    if (i + 1 < i1) {
      e_n = __builtin_amdgcn_readfirstlane(elist[i + 1]);
      s_n = __builtin_amdgcn_readfirstlane(srcs[e_n]);
    }
    f32x2 xv = ldbf2v(xl + (size_t)s * D1 + c);
    const float* ear = eatt + (size_t)e * ED;
    f32x2 et = {0.f, 0.f};
#pragma unroll
    for (int j = 0; j < ED; j += 2) {
      f32x2 t = ldf2v(ear + j);
      et += (f32x2){t.x, t.x} * we[j];
      et += (f32x2){t.y, t.y} * we[j + 1];
    }
    f32x2 mm = xv + rv + et;
    f32x2 pos = {fmaxf(mm.x, 0.f), fmaxf(mm.y, 0.f)};
    f32x2 neg = {fminf(mm.x, 0.f), fminf(mm.y, 0.f)};
    mm = pos + 0.2f * neg;                 // leaky_relu
    float al = mm.x * av.x + mm.y * av.y;
#pragma unroll
    for (int o = 32; o; o >>= 1) al += __shfl_xor(al, o, 64);
    float nm = fmaxf(m, al);
    float sc = __expf(m - nm);
    float pr = __expf(al - nm);
    den = den * sc + pr;
    acc = acc * sc + (f32x2){pr, pr} * xv;
    m = nm;
    e = e_n;
    s = s_n;
  }
  float inv = 1.f / (den + 1e-16f);
  f32x2 sk = ldbf2v(skip + (size_t)node * D1 + c);
  float o0 = acc.x * inv + bias[c] + sk.x;
  float o1 = acc.y * inv + bias[c + 1] + sk.y;

  // LayerNorm over 512 (block-wide) + ELU
  float s1 = o0 + o1, s2 = o0 * o0 + o1 * o1;
#pragma unroll
  for (int of = 32; of; of >>= 1) {
    s1 += __shfl_xor(s1, of, 64);
    s2 += __shfl_xor(s2, of, 64);
  }
  __shared__ float r1[4], r2[4];
  if (l == 0) { r1[w] = s1; r2[w] = s2; }
  __syncthreads();
  float S1 = r1[0] + r1[1] + r1[2] + r1[3];
  float S2 = r2[0] + r2[1] + r2[2] + r2[3];
  float mu = S1 * (1.f / 512.f);
  float var = fmaxf(S2 * (1.f / 512.f) - mu * mu, 0.f);
  float rs = rsqrtf(var + 1e-5f);
  float y0 = (o0 - mu) * rs * g[c] + be[c];
  float y1 = (o1 - mu) * rs * g[c + 1] + be[c + 1];
  y0 = y0 > 0.f ? y0 : __expf(fminf(y0, 0.f)) - 1.f;
  y1 = y1 > 0.f ? y1 : __expf(fminf(y1, 0.f)) - 1.f;
  hout[(size_t)node * D1 + c] = (bf16)y0;
  hout[(size_t)node * D1 + c + 1] = (bf16)y1;
}

// ---- Layer-2 FUSED: aggregate + bias + skip + final LN -> d_out -----------
// 4 nodes per block (wave w = node), lane owns cols 2l, 2l+1.
__global__ __launch_bounds__(256) void l2_agg_f(
    const float* __restrict__ xl, const float* __restrict__ xr,
    const float* __restrict__ skip, const float* __restrict__ eatt,
    const float* __restrict__ We, const float* __restrict__ att,
    const float* __restrict__ bias, const float* __restrict__ g,
    const float* __restrict__ be, const int* __restrict__ srcs,
    const int* __restrict__ offs, const int* __restrict__ elist,
    float* __restrict__ outp) {
  int tid = threadIdx.x;
  int w = tid >> 6, l = tid & 63;
  int node = blockIdx.x * 4 + w;
  if (node >= NN) return;
  int c = 2 * l;
  f32x2 we[ED];
#pragma unroll
  for (int j = 0; j < ED; j++) {
    we[j] = (f32x2){We[(size_t)j * DOUT + c], We[(size_t)j * DOUT + c + 1]};
  }
  f32x2 av = ldf2v(att + c);
  f32x2 rv = ldf2v(xr + (size_t)node * DOUT + c);
  float m = -3.0e38f, den = 0.f;
  f32x2 acc = {0.f, 0.f};
  int i0 = offs[node], i1 = offs[node + 1];
  i0 = max(0, min(i0, EE));
  i1 = max(i0, min(i1, EE));
  int e = 0, s = 0;
  if (i0 < i1) {
    e = __builtin_amdgcn_readfirstlane(elist[i0]);
    s = __builtin_amdgcn_readfirstlane(srcs[e]);
  }
  for (int i = i0; i < i1; i++) {
    int e_n = e, s_n = s;
    if (i + 1 < i1) {
      e_n = __builtin_amdgcn_readfirstlane(elist[i + 1]);
      s_n = __builtin_amdgcn_readfirstlane(srcs[e_n]);
    }
    f32x2 xv = ldf2v(xl + (size_t)s * DOUT + c);
    const float* ear = eatt + (size_t)e * ED;
    f32x2 et = {0.f, 0.f};
#pragma unroll
    for (int j = 0; j < ED; j += 2) {
      f32x2 t = ldf2v(ear + j);
      et += (f32x2){t.x, t.x} * we[j];
      et += (f32x2){t.y, t.y} * we[j + 1];
    }
    f32x2 mm = xv + rv + et;
    f32x2 pos = {fmaxf(mm.x, 0.f), fmaxf(mm.y, 0.f)};
    f32x2 neg = {fminf(mm.x, 0.f), fminf(mm.y, 0.f)};
    mm = pos + 0.2f * neg;
    float al = mm.x * av.x + mm.y * av.y;
#pragma unroll
    for (int o = 32; o; o >>= 1) al += __shfl_xor(al, o, 64);
    float nm = fmaxf(m, al);
    float sc = __expf(m - nm);
    float pr = __expf(al - nm);
    den = den * sc + pr;
    acc = acc * sc + (f32x2){pr, pr} * xv;
    m = nm;
    e = e_n;
    s = s_n;
  }
  float inv = 1.f / (den + 1e-16f);
  f32x2 sk = ldf2v(skip + (size_t)node * DOUT + c);
  float o0 = acc.x * inv + bias[c] + sk.x;
  float o1 = acc.y * inv + bias[c + 1] + sk.y;
  float s1 = o0 + o1, s2 = o0 * o0 + o1 * o1;
#pragma unroll
  for (int of = 32; of; of >>= 1) {
    s1 += __shfl_xor(s1, of, 64);
    s2 += __shfl_xor(s2, of, 64);
  }
  float mu = s1 * (1.f / 128.f);
  float var = fmaxf(s2 * (1.f / 128.f) - mu * mu, 0.f);
  float rs = rsqrtf(var + 1e-5f);
  outp[(size_t)node * DOUT + c] = (o0 - mu) * rs * g[c] + be[c];
  outp[(size_t)node * DOUT + c + 1] = (o1 - mu) * rs * g[c + 1] + be[c + 1];
}

// ---------------- fallback kernels (r12): agg w/o LN, lnelu, ln128 ---------
__global__ __launch_bounds__(256) void l1_agg(
    const bf16* __restrict__ xl, const bf16* xr,
    const float* __restrict__ eatt, const float* __restrict__ We,
    const float* __restrict__ att, const float* __restrict__ bias,
    const int* __restrict__ srcs, const int* __restrict__ offs,
    const int* __restrict__ elist, bf16* hout) {
  int node = blockIdx.x;
  int tid = threadIdx.x;
  int w = tid >> 6, l = tid & 63;
  int c = w * 128 + 2 * l;
  f32x2 we[ED];
#pragma unroll
  for (int j = 0; j < ED; j++) {
    we[j] = (f32x2){We[(size_t)j * D1 + c], We[(size_t)j * D1 + c + 1]};
  }
  f32x2 av = ldf2v(att + c);
  f32x2 rv = ldbf2v(xr + (size_t)node * D1 + c);
  float m = -3.0e38f, den = 0.f;
  f32x2 acc = {0.f, 0.f};
  int i0 = offs[node], i1 = offs[node + 1];
  i0 = max(0, min(i0, EE));
  i1 = max(i0, min(i1, EE));
  int e = 0, s = 0;
  if (i0 < i1) {
    e = __builtin_amdgcn_readfirstlane(elist[i0]);
    s = __builtin_amdgcn_readfirstlane(srcs[e]);
  }
  for (int i = i0; i < i1; i++) {
    int e_n = e, s_n = s;
    if (i + 1 < i1) {
      e_n = __builtin_amdgcn_readfirstlane(elist[i + 1]);
      s_n = __builtin_amdgcn_readfirstlane(srcs[e_n]);
    }
    f32x2 xv = ldbf2v(xl + (size_t)s * D1 + c);
    const float* ear = eatt + (size_t)e * ED;
    f32x2 et = {0.f, 0.f};
#pragma unroll
    for (int j = 0; j < ED; j += 2) {
      f32x2 t = ldf2v(ear + j);
      et += (f32x2){t.x, t.x} * we[j];
      et += (f32x2){t.y, t.y} * we[j + 1];
    }
    f32x2 mm = xv + rv + et;
    f32x2 pos = {fmaxf(mm.x, 0.f), fmaxf(mm.y, 0.f)};
    f32x2 neg = {fminf(mm.x, 0.f), fminf(mm.y, 0.f)};
    mm = pos + 0.2f * neg;
    float al = mm.x * av.x + mm.y * av.y;
#pragma unroll
    for (int o = 32; o; o >>= 1) al += __shfl_xor(al, o, 64);
    float nm = fmaxf(m, al);
    float sc = __expf(m - nm);
    float pr = __expf(al - nm);
    den = den * sc + pr;
    acc = acc * sc + (f32x2){pr, pr} * xv;
    m = nm;
    e = e_n;
    s = s_n;
  }
  float inv = 1.f / (den + 1e-16f);
  hout[(size_t)node * D1 + c] = (bf16)(acc.x * inv + bias[c]);
  hout[(size_t)node * D1 + c + 1] = (bf16)(acc.y * inv + bias[c + 1]);
}

__global__ __launch_bounds__(256) void l2_agg(
    const float* __restrict__ xl, const float* xr,
    const float* __restrict__ eatt, const float* __restrict__ We,
    const float* __restrict__ att, const float* __restrict__ bias,
    const int* __restrict__ srcs, const int* __restrict__ offs,
    const int* __restrict__ elist, float* hout) {
  int tid = threadIdx.x;
  int w = tid >> 6, l = tid & 63;
  int node = blockIdx.x * 4 + w;
  if (node >= NN) return;
  int c = 2 * l;
  f32x2 we[ED];
#pragma unroll
  for (int j = 0; j < ED; j++) {
    we[j] = (f32x2){We[(size_t)j * DOUT + c], We[(size_t)j * DOUT + c + 1]};
  }
  f32x2 av = ldf2v(att + c);
  f32x2 rv = ldf2v(xr + (size_t)node * DOUT + c);
  float m = -3.0e38f, den = 0.f;
  f32x2 acc = {0.f, 0.f};
  int i0 = offs[node], i1 = offs[node + 1];
  i0 = max(0, min(i0, EE));
  i1 = max(i0, min(i1, EE));
  int e = 0, s = 0;
  if (i0 < i1) {
    e = __builtin_amdgcn_readfirstlane(elist[i0]);
    s = __builtin_amdgcn_readfirstlane(srcs[e]);
  }
  for (int i = i0; i < i1; i++) {
    int e_n = e, s_n = s;
    if (i + 1 < i1) {
      e_n = __builtin_amdgcn_readfirstlane(elist[i + 1]);
      s_n = __builtin_amdgcn_readfirstlane(srcs[e_n]);
    }
    f32x2 xv = ldf2v(xl + (size_t)s * DOUT + c);
    const float* ear = eatt + (size_t)e * ED;
    f32x2 et = {0.f, 0.f};
#pragma unroll
    for (int j = 0; j < ED; j += 2) {
      f32x2 t = ldf2v(ear + j);
      et += (f32x2){t.x, t.x} * we[j];
      et += (f32x2){t.y, t.y} * we[j + 1];
    }
    f32x2 mm = xv + rv + et;
    f32x2 pos = {fmaxf(mm.x, 0.f), fmaxf(mm.y, 0.f)};
    f32x2 neg = {fminf(mm.x, 0.f), fminf(mm.y, 0.f)};
    mm = pos + 0.2f * neg;
    float al = mm.x * av.x + mm.y * av.y;
#pragma unroll
    for (int o = 32; o; o >>= 1) al += __shfl_xor(al, o, 64);
    float nm = fmaxf(m, al);
    float sc = __expf(m - nm);
    float pr = __expf(al - nm);
    den = den * sc + pr;
    acc = acc * sc + (f32x2){pr, pr} * xv;
    m = nm;
    e = e_n;
    s = s_n;
  }
  float inv = 1.f / (den + 1e-16f);
  hout[(size_t)node * DOUT + c] = acc.x * inv + bias[c];
  hout[(size_t)node * DOUT + c + 1] = acc.y * inv + bias[c + 1];
}

__global__ __launch_bounds__(256) void lnelu_k(bf16* buf,
                                               const float* __restrict__ g,
                                               const float* __restrict__ be) {
  int node = blockIdx.x, tid = threadIdx.x;
  int w = tid >> 6, l = tid & 63;
  int c = tid * 2;
  f32x2 o = ldbf2v(buf + (size_t)node * D1 + c);
  float s1 = o.x + o.y, s2 = o.x * o.x + o.y * o.y;
#pragma unroll
  for (int of = 32; of; of >>= 1) {
    s1 += __shfl_xor(s1, of, 64);
    s2 += __shfl_xor(s2, of, 64);
  }
  __shared__ float r1[4], r2[4];
  if (l == 0) { r1[w] = s1; r2[w] = s2; }
  __syncthreads();
  float S1 = r1[0] + r1[1] + r1[2] + r1[3];
  float S2 = r2[0] + r2[1] + r2[2] + r2[3];
  float mu = S1 * (1.f / 512.f);
  float var = fmaxf(S2 * (1.f / 512.f) - mu * mu, 0.f);
  float rs = rsqrtf(var + 1e-5f);
  float y0 = (o.x - mu) * rs * g[c] + be[c];
  float y1 = (o.y - mu) * rs * g[c + 1] + be[c + 1];
  y0 = y0 > 0.f ? y0 : __expf(fminf(y0, 0.f)) - 1.f;
  y1 = y1 > 0.f ? y1 : __expf(fminf(y1, 0.f)) - 1.f;
  buf[(size_t)node * D1 + c] = (bf16)y0;
  buf[(size_t)node * D1 + c + 1] = (bf16)y1;
}

__global__ __launch_bounds__(256) void ln128_k(const float* __restrict__ buf,
                                               const float* __restrict__ g,
                                               const float* __restrict__ be,
                                               float* __restrict__ outp) {
  int tid = threadIdx.x;
  int w = tid >> 6, l = tid & 63;
  int node = blockIdx.x * 4 + w;
  if (node >= NN) return;
  int c = 2 * l;
  f32x2 o = ldf2v(buf + (size_t)node * DOUT + c);
  float s1 = o.x + o.y, s2 = o.x * o.x + o.y * o.y;
#pragma unroll
  for (int of = 32; of; of >>= 1) {
    s1 += __shfl_xor(s1, of, 64);
    s2 += __shfl_xor(s2, of, 64);
  }
  float mu = s1 * (1.f / 128.f);
  float var = fmaxf(s2 * (1.f / 128.f) - mu * mu, 0.f);
  float rs = rsqrtf(var + 1e-5f);
  outp[(size_t)node * DOUT + c] = (o.x - mu) * rs * g[c] + be[c];
  outp[(size_t)node * DOUT + c + 1] = (o.y - mu) * rs * g[c + 1] + be[c + 1];
}

extern "C" void kernel_launch(void* const* d_in, const int* in_sizes, int n_in,
                              void* d_out, int out_size, void* d_ws, size_t ws_size,
                              hipStream_t stream) {
  const float* x = (const float*)d_in[0];
  const void* ei = d_in[1];
  const float* eattr = (const float*)d_in[2];
  const float* W1l = (const float*)d_in[3];
  const float* b1l = (const float*)d_in[4];
  const float* W1r = (const float*)d_in[5];
  const float* b1r = (const float*)d_in[6];
  const float* We1 = (const float*)d_in[7];
  const float* att1 = (const float*)d_in[8];
  const float* bias1 = (const float*)d_in[9];
  const float* Wsk1 = (const float*)d_in[10];
  const float* bsk1 = (const float*)d_in[11];
  const float* g1 = (const float*)d_in[12];
  const float* be1 = (const float*)d_in[13];
  const float* W2l = (const float*)d_in[14];
  const float* b2l = (const float*)d_in[15];
  const float* W2r = (const float*)d_in[16];
  const float* b2r = (const float*)d_in[17];
  const float* We2 = (const float*)d_in[18];
  const float* att2 = (const float*)d_in[19];
  const float* bias2 = (const float*)d_in[20];
  const float* Wsk2 = (const float*)d_in[21];
  const float* bsk2 = (const float*)d_in[22];
  const float* g2 = (const float*)d_in[23];
  const float* be2 = (const float*)d_in[24];

  // workspace carve (256B aligned)
  char* p = (char*)d_ws;
  size_t off = 0;
  auto carve = [&](size_t bytes) {
    void* r = p + off;
    off = (off + bytes + 255) & ~(size_t)255;
    return r;
  };
  int* flag = (int*)carve(sizeof(int));
  int* srcD = (int*)carve(EE * sizeof(int));
  int* dstD = (int*)carve(EE * sizeof(int));
  int* deg = (int*)carve(NN * sizeof(int));
  int* offs = (int*)carve((NN + 1) * sizeof(int));
  int* cursor = (int*)carve(NN * sizeof(int));
  int* elist = (int*)carve(EE * sizeof(int));
  bf16* bufA = (bf16*)carve((size_t)NN * D1 * 2);  // xl1; then f32 x2l/x2r
  bf16* bufB = (bf16*)carve((size_t)NN * D1 * 2);  // xr1 -> h
  size_t base_need = off;
  bf16* bufC = (bf16*)carve((size_t)NN * D1 * 2);  // skip1 bf16 / skip2 f32
  bool fused = (off <= ws_size);                   // ws_size decides path

  float* q0 = (float*)bufA;              // x2l (f32)
  float* q1 = q0 + (size_t)NN * DOUT;    // x2r (f32)
  float* sk2 = (float*)bufC;             // skip2 (f32, fused path)

  // edge_index detect + convert
  zero_k<<<1, 256, 0, stream>>>(flag, 1);
  detflag_k<<<(EE + 255) / 256, 256, 0, stream>>>((const int*)ei, flag);
  conv_k<<<(EE + 255) / 256, 256, 0, stream>>>(ei, flag, srcD, dstD);

  // CSR build (by dst)
  zero_k<<<(NN + 255) / 256, 256, 0, stream>>>(deg, NN);
  hist_k<<<(EE + 255) / 256, 256, 0, stream>>>(dstD, deg, EE);
  scan_k<<<1, 1024, 0, stream>>>(deg, offs, cursor, NN);
  scatter_k<<<(EE + 255) / 256, 256, 0, stream>>>(dstD, cursor, elist, EE);

  if (fused) {
    // layer-1: (xl, xr, skip1) = x @ (W1l, W1r, Wsk1) + biases
    gemm3_t<float, bf16><<<dim3(D1 / 64, NN / 16), 256, 0, stream>>>(
        x, W1l, W1r, Wsk1, b1l, b1r, bsk1, bufA, bufB, bufC, D1, FIN);
    // fused agg + bias + skip + LN + ELU -> h (in bufB)
    l1_agg_f<<<NN, 256, 0, stream>>>(bufA, bufB, bufC, eattr, We1, att1,
                                     bias1, g1, be1, srcD, offs, elist, bufB);
    // layer-2: (x2l, x2r, skip2) = h @ (W2l, W2r, Wsk2) + biases (f32 out)
    gemm3_t<bf16, float><<<dim3(DOUT / 64, NN / 16), 256, 0, stream>>>(
        bufB, W2l, W2r, Wsk2, b2l, b2r, bsk2, q0, q1, sk2, DOUT, D1);
    // fused agg + bias + skip + final LN -> d_out
    l2_agg_f<<<(NN + 3) / 4, 256, 0, stream>>>(q0, q1, sk2, eattr, We2, att2,
                                               bias2, g2, be2, srcD, offs,
                                               elist, (float*)d_out);
  } else {
    // r12 fallback path (fits in base_need bytes)
    (void)base_need;
    gemm2_t<float, bf16><<<dim3(D1 / 64, NN / 16), 256, 0, stream>>>(
        x, W1l, W1r, b1l, b1r, bufA, bufB, D1, FIN);
    l1_agg<<<NN, 256, 0, stream>>>(bufA, bufB, eattr, We1, att1, bias1,
                                   srcD, offs, elist, bufB);
    gemm_t<float, bf16, true><<<dim3(D1 / 64, NN / 16), 256, 0, stream>>>(
        x, Wsk1, bsk1, bufB, D1, FIN);
    lnelu_k<<<NN, 256, 0, stream>>>(bufB, g1, be1);
    gemm2_t<bf16, float><<<dim3(DOUT / 64, NN / 16), 256, 0, stream>>>(
        bufB, W2l, W2r, b2l, b2r, q0, q1, DOUT, D1);
    l2_agg<<<(NN + 3) / 4, 256, 0, stream>>>(q0, q1, eattr, We2, att2, bias2,
                                             srcD, offs, elist, q1);
    gemm_t<bf16, float, true><<<dim3(DOUT / 64, NN / 16), 256, 0, stream>>>(
        bufB, Wsk2, bsk2, q1, DOUT, D1);
    ln128_k<<<(NN + 3) / 4, 256, 0, stream>>>(q1, g2, be2, (float*)d_out);
  }

  (void)in_sizes; (void)n_in; (void)out_size;
}